// Round 8
// baseline (587.674 us; speedup 1.0000x reference)
//
#include <hip/hip_runtime.h>
#include <hip/hip_bf16.h>

// Attention_50946902065218: Bahdanau-style attention
// B=256, L=196, E=2048, D=1024, A=512
// v8 pipeline (big workspace):
//  k_wepack : We fp32 -> bf16, [kb][n][slot^swz(n)][e] pre-swizzled (2 MB)
//  k_encpack: enc fp32 -> bf16, tile-contiguous pre-swizzled
//             [mt][kb][mr][slot^swz(mr)][e] (206 MB in ws)
//  k_bias2  : bias2[b][a] = be+bd+dec@Wd  (64 blocks x 4 batches)
//  k_gemm_bf16: pure m97-structure GEMM: 128x128 tile, 4 waves, BK=32,
//             BOTH tiles via global_load_lds from pre-swizzled bf16,
//             stage(t+1)->compute(t)->barrier. No reg-staging path.
//  k_softmax: sum 4 partials + mask + softmax -> alpha
//  k_awe_bf16: alpha-weighted sum reading packed bf16 enc (205 MB)
// Fallback (small ws): k_gemm_f32 stages fp32 A into LDS (cvt on fragment
// read) and k_awe_f32 reads fp32 enc. Same results, slower.

#define B_ 256
#define L_ 196
#define E_ 2048
#define D_ 1024
#define A_ 512
#define M_TOT (B_ * L_)   // 50176 = 392 * 128

typedef __attribute__((ext_vector_type(8))) short bf16x8;
typedef __attribute__((ext_vector_type(4))) float f32x4;

static __device__ __forceinline__ unsigned short f2bf(float f) {
    union { float f; unsigned u; } u{f};
    unsigned r = u.u + 0x7fffu + ((u.u >> 16) & 1u);   // RNE
    return (unsigned short)(r >> 16);
}
static __device__ __forceinline__ unsigned int pk2(float x, float y) {
    __hip_bfloat162 h = __float22bfloat162_rn(float2{x, y});   // v_cvt_pk_bf16_f32
    return *reinterpret_cast<unsigned int*>(&h);
}
static __device__ __forceinline__ void gload_lds16(const void* g, void* l) {
    __builtin_amdgcn_global_load_lds(
        (const __attribute__((address_space(1))) unsigned int*)g,
        (__attribute__((address_space(3))) unsigned int*)l, 16, 0, 0);
}

// ---------------- k_wepack: We (E x A fp32) -> WeP bf16 ----------------------
// (k,n): kb=k>>5, slot=(k>>3)&3, e=k&7; stored slot' = slot ^ ((n>>1)&3).
// Index = kb*16384 + n*32 + slot'*8 + e. Fragment read (16 lanes n=base+lr,
// fixed slot) spreads over 8 (parity,slot) combos -> 2 lanes/bank (free).
__global__ __launch_bounds__(256) void k_wepack(const float* __restrict__ We,
                                                unsigned short* __restrict__ WeP) {
    int i = blockIdx.x * 256 + threadIdx.x;
    int k = i >> 9, n = i & 511;
    int kb = k >> 5, slot = (k >> 3) & 3, e = k & 7;
    int slotE = slot ^ ((n >> 1) & 3);
    WeP[(kb << 14) + (n << 5) + (slotE << 3) + e] = f2bf(We[i]);
}

// ---------------- k_encpack: enc fp32 -> encP bf16 (tiled + swizzled) --------
// encP[mt*262144 + kb*4096 + mr*32 + slot'*8 + e], slot' = slot ^ ((mr>>1)&3)
// Grid 392*8 blocks; block = (mt, group of 8 kb). Thread: mr=t>>1, half=t&1.
__global__ __launch_bounds__(256) void k_encpack(const float* __restrict__ enc,
                                                 unsigned short* __restrict__ encP) {
    int mt = blockIdx.x >> 3, kbg = blockIdx.x & 7;
    int t = threadIdx.x, mr = t >> 1, half = t & 1;
    const float* src0 = enc + (size_t)(mt * 128 + mr) * E_ + half * 16;
    unsigned short* dst0 = encP + (size_t)mt * 262144 + mr * 32;
    int sw = (mr >> 1) & 3;
    #pragma unroll
    for (int c = 0; c < 8; c++) {
        int kb = kbg * 8 + c;
        const float* s = src0 + kb * 32;
        float4 f0 = *reinterpret_cast<const float4*>(s);
        float4 f1 = *reinterpret_cast<const float4*>(s + 4);
        float4 f2 = *reinterpret_cast<const float4*>(s + 8);
        float4 f3 = *reinterpret_cast<const float4*>(s + 12);
        uint4 g0, g1;
        g0.x = pk2(f0.x, f0.y); g0.y = pk2(f0.z, f0.w);
        g0.z = pk2(f1.x, f1.y); g0.w = pk2(f1.z, f1.w);
        g1.x = pk2(f2.x, f2.y); g1.y = pk2(f2.z, f2.w);
        g1.z = pk2(f3.x, f3.y); g1.w = pk2(f3.z, f3.w);
        unsigned short* d = dst0 + kb * 4096;
        *reinterpret_cast<uint4*>(d + (((half * 2 + 0) ^ sw) << 3)) = g0;
        *reinterpret_cast<uint4*>(d + (((half * 2 + 1) ^ sw) << 3)) = g1;
    }
}

// ---------------- k_bias2: bias2 = be + bd + dec @ Wd ------------------------
// 64 blocks x 4 batches each; Wd streamed once per block (L2/L3 resident).
__global__ __launch_bounds__(256) void k_bias2(const float* __restrict__ dec,
                                               const float* __restrict__ Wd,
                                               const float* __restrict__ be,
                                               const float* __restrict__ bd,
                                               float* __restrict__ bias2) {
    int b0 = blockIdx.x * 4, t = threadIdx.x;
    __shared__ float ds[4][D_];
    for (int i = t; i < 4 * D_; i += 256) ds[i >> 10][i & 1023] = dec[(size_t)b0 * D_ + i];
    __syncthreads();
    #pragma unroll
    for (int p = 0; p < 2; p++) {
        int a = p * 256 + t;
        float a0 = 0.f, a1 = 0.f, a2 = 0.f, a3 = 0.f;
        #pragma unroll 4
        for (int d = 0; d < D_; d++) {
            float w = Wd[d * A_ + a];
            a0 += ds[0][d] * w; a1 += ds[1][d] * w;
            a2 += ds[2][d] * w; a3 += ds[3][d] * w;
        }
        float bb = be[a] + bd[a];
        bias2[(b0 + 0) * A_ + a] = a0 + bb;
        bias2[(b0 + 1) * A_ + a] = a1 + bb;
        bias2[(b0 + 2) * A_ + a] = a2 + bb;
        bias2[(b0 + 3) * A_ + a] = a3 + bb;
    }
}

// ---------------- k_gemm_bf16: pure global_load_lds MFMA GEMM ----------------
// 1568 blocks (392 mt x 4 nt, XCD-chunked), 256 thr, 4 waves 2x2, wave 64x64.
__global__ __launch_bounds__(256) void k_gemm_bf16(
        const unsigned short* __restrict__ encP,
        const unsigned short* __restrict__ WeP,
        const float* __restrict__ bias2,
        const float* __restrict__ wf,
        float* __restrict__ scoresP) {
    __shared__ __align__(16) unsigned short aL[2][4096];   // 8 KB each
    __shared__ __align__(16) unsigned short bL[2][4096];   // 8 KB each
    __shared__ float score_lds[4][64];

    const int tid = threadIdx.x;
    const int raw = blockIdx.x;                 // 1568 = 8 * 196
    const int wg = (raw & 7) * 196 + (raw >> 3);
    const int mt = wg >> 2, nt = wg & 3;
    const int m0 = mt * 128;

    const int lane = tid & 63;
    const int wid = tid >> 6;
    const int wm = wid >> 1, wn = wid & 1;
    const int kg = lane >> 4, lr = lane & 15;

    const unsigned short* aSrc = encP + (size_t)mt * 262144 + tid * 8;
    const unsigned short* bSrc = WeP + nt * 4096 + tid * 8;

    auto stage = [&](int kb, int buf) {
        const unsigned short* sa = aSrc + (kb << 12);
        const unsigned short* sb = bSrc + (kb << 14);
        gload_lds16(sa,        &aL[buf][tid * 8]);
        gload_lds16(sa + 2048, &aL[buf][2048 + tid * 8]);
        gload_lds16(sb,        &bL[buf][tid * 8]);
        gload_lds16(sb + 2048, &bL[buf][2048 + tid * 8]);
    };

    f32x4 acc[4][4];
    #pragma unroll
    for (int i = 0; i < 4; i++)
        #pragma unroll
        for (int j = 0; j < 4; j++) acc[i][j] = (f32x4){0.f, 0.f, 0.f, 0.f};

    auto computeTile = [&](int buf) {
        bf16x8 bfr[4];
        #pragma unroll
        for (int j = 0; j < 4; j++) {
            int n = wn * 64 + j * 16 + lr;
            bfr[j] = *reinterpret_cast<const bf16x8*>(
                &bL[buf][n * 32 + ((kg ^ ((n >> 1) & 3)) << 3)]);
        }
        #pragma unroll
        for (int i = 0; i < 4; i++) {
            int row = wm * 64 + i * 16 + lr;
            bf16x8 af = *reinterpret_cast<const bf16x8*>(
                &aL[buf][row * 32 + ((kg ^ ((row >> 1) & 3)) << 3)]);
            #pragma unroll
            for (int j = 0; j < 4; j++)
                acc[i][j] = __builtin_amdgcn_mfma_f32_16x16x32_bf16(
                    af, bfr[j], acc[i][j], 0, 0, 0);
        }
    };

    stage(0, 0);
    __syncthreads();
    int buf = 0;
    for (int kb = 0; kb < 64; kb++) {
        if (kb < 63) stage(kb + 1, buf ^ 1);
        computeTile(buf);
        __syncthreads();
        buf ^= 1;
    }

    // epilogue: tanh + wf-dot over this block's 128 cols -> partial scores
    #pragma unroll
    for (int i = 0; i < 4; i++) {
        #pragma unroll
        for (int r = 0; r < 4; r++) {
            int Rw = i * 16 + kg * 4 + r;       // C/D: col=lane&15, row=(lane>>4)*4+reg
            int gm = m0 + wm * 64 + Rw;
            int bg = gm / L_;
            float sum = 0.f;
            #pragma unroll
            for (int j = 0; j < 4; j++) {
                int C = nt * 128 + wn * 64 + j * 16 + lr;
                float x = acc[i][j][r] + bias2[bg * A_ + C];
                float ex = __expf(2.f * x);     // tanh = 1 - 2/(e^2x + 1)
                sum += wf[C] * (1.f - 2.f * __builtin_amdgcn_rcpf(ex + 1.f));
            }
            #pragma unroll
            for (int mk = 1; mk < 16; mk <<= 1) sum += __shfl_xor(sum, mk);
            if (lr == 0) score_lds[wid][Rw] = sum;
        }
    }
    __syncthreads();
    if (tid < 128) {
        int wmp = tid >> 6, rl = tid & 63;
        float s = score_lds[wmp * 2][rl] + score_lds[wmp * 2 + 1][rl];
        scoresP[nt * M_TOT + m0 + wmp * 64 + rl] = s;
    }
}

// ---------------- k_gemm_f32: fallback (fp32 A staged in LDS) ----------------
__global__ __launch_bounds__(256) void k_gemm_f32(
        const float* __restrict__ enc,
        const unsigned short* __restrict__ WeP,
        const float* __restrict__ bias2,
        const float* __restrict__ wf,
        float* __restrict__ scoresP) {
    __shared__ __align__(16) float aF[2][4096];             // 16 KB each
    __shared__ __align__(16) unsigned short bL[2][4096];    // 8 KB each
    __shared__ float score_lds[4][64];

    const int tid = threadIdx.x;
    const int raw = blockIdx.x;
    const int wg = (raw & 7) * 196 + (raw >> 3);
    const int mt = wg >> 2, nt = wg & 3;
    const int m0 = mt * 128;

    const int lane = tid & 63;
    const int wid = tid >> 6;
    const int wm = wid >> 1, wn = wid & 1;
    const int kg = lane >> 4, lr = lane & 15;

    const unsigned short* bSrc = WeP + nt * 4096 + tid * 8;

    auto stage = [&](int kb, int buf) {
        #pragma unroll
        for (int c = 0; c < 4; c++) {
            int gidx = c * 256 + tid;
            int r = gidx >> 3, k16 = gidx & 7;
            int kgs = k16 >> 1, h = k16 & 1;
            int kgp = kgs ^ ((r >> 1) & 3);
            const float* s = enc + (size_t)(m0 + r) * E_ + kb * 32 + kgp * 8 + h * 4;
            gload_lds16(s, &aF[buf][gidx * 4]);
        }
        const unsigned short* sb = bSrc + (kb << 14);
        gload_lds16(sb,        &bL[buf][tid * 8]);
        gload_lds16(sb + 2048, &bL[buf][2048 + tid * 8]);
    };

    f32x4 acc[4][4];
    #pragma unroll
    for (int i = 0; i < 4; i++)
        #pragma unroll
        for (int j = 0; j < 4; j++) acc[i][j] = (f32x4){0.f, 0.f, 0.f, 0.f};

    auto computeTile = [&](int buf) {
        bf16x8 bfr[4];
        #pragma unroll
        for (int j = 0; j < 4; j++) {
            int n = wn * 64 + j * 16 + lr;
            bfr[j] = *reinterpret_cast<const bf16x8*>(
                &bL[buf][n * 32 + ((kg ^ ((n >> 1) & 3)) << 3)]);
        }
        #pragma unroll
        for (int i = 0; i < 4; i++) {
            int row = wm * 64 + i * 16 + lr;
            int off = row * 32 + ((kg ^ ((row >> 1) & 3)) << 3);
            float4 f0 = *reinterpret_cast<const float4*>(&aF[buf][off]);
            float4 f1 = *reinterpret_cast<const float4*>(&aF[buf][off + 4]);
            union { uint4 q; bf16x8 v; } u;
            u.q.x = pk2(f0.x, f0.y); u.q.y = pk2(f0.z, f0.w);
            u.q.z = pk2(f1.x, f1.y); u.q.w = pk2(f1.z, f1.w);
            #pragma unroll
            for (int j = 0; j < 4; j++)
                acc[i][j] = __builtin_amdgcn_mfma_f32_16x16x32_bf16(
                    u.v, bfr[j], acc[i][j], 0, 0, 0);
        }
    };

    stage(0, 0);
    __syncthreads();
    int buf = 0;
    for (int kb = 0; kb < 64; kb++) {
        if (kb < 63) stage(kb + 1, buf ^ 1);
        computeTile(buf);
        __syncthreads();
        buf ^= 1;
    }

    #pragma unroll
    for (int i = 0; i < 4; i++) {
        #pragma unroll
        for (int r = 0; r < 4; r++) {
            int Rw = i * 16 + kg * 4 + r;
            int gm = m0 + wm * 64 + Rw;
            int bg = gm / L_;
            float sum = 0.f;
            #pragma unroll
            for (int j = 0; j < 4; j++) {
                int C = nt * 128 + wn * 64 + j * 16 + lr;
                float x = acc[i][j][r] + bias2[bg * A_ + C];
                float ex = __expf(2.f * x);
                sum += wf[C] * (1.f - 2.f * __builtin_amdgcn_rcpf(ex + 1.f));
            }
            #pragma unroll
            for (int mk = 1; mk < 16; mk <<= 1) sum += __shfl_xor(sum, mk);
            if (lr == 0) score_lds[wid][Rw] = sum;
        }
    }
    __syncthreads();
    if (tid < 128) {
        int wmp = tid >> 6, rl = tid & 63;
        float s = score_lds[wmp * 2][rl] + score_lds[wmp * 2 + 1][rl];
        scoresP[nt * M_TOT + m0 + wmp * 64 + rl] = s;
    }
}

// ---------------- k_softmax: sum 4 partials + mask + softmax -----------------
__global__ __launch_bounds__(256) void k_softmax(const float* __restrict__ scoresP,
                                                 const int* __restrict__ mask,
                                                 const float* __restrict__ bfp,
                                                 float* __restrict__ alpha) {
    int b = blockIdx.x, t = threadIdx.x;
    float bfv = bfp[0];
    float v = -INFINITY;
    if (t < L_) {
        int idx = b * L_ + t;
        float sc = scoresP[idx] + scoresP[M_TOT + idx] +
                   scoresP[2 * M_TOT + idx] + scoresP[3 * M_TOT + idx];
        v = (mask[idx] == 0) ? -1e9f : (sc + bfv);
    }
    __shared__ float redm[4], reds[4];
    float m = v;
    #pragma unroll
    for (int s = 1; s < 64; s <<= 1) m = fmaxf(m, __shfl_xor(m, s));
    int w = t >> 6;
    if ((t & 63) == 0) redm[w] = m;
    __syncthreads();
    m = fmaxf(fmaxf(redm[0], redm[1]), fmaxf(redm[2], redm[3]));
    float e = (t < L_) ? expf(v - m) : 0.f;
    float s = e;
    #pragma unroll
    for (int k = 1; k < 64; k <<= 1) s += __shfl_xor(s, k);
    if ((t & 63) == 0) reds[w] = s;
    __syncthreads();
    s = reds[0] + reds[1] + reds[2] + reds[3];
    if (t < L_) alpha[b * L_ + t] = e / s;
}

// ---------------- k_awe_bf16: weighted sum from packed bf16 enc --------------
// 1024 blocks = (b, quarter q of 49 rows), 256 thr (8 e each), 7-deep loads.
__global__ __launch_bounds__(256) void k_awe_bf16(const unsigned short* __restrict__ encP,
                                                  const float* __restrict__ alpha,
                                                  float* __restrict__ aweP) {
    int b = blockIdx.x >> 2, q = blockIdx.x & 3, t = threadIdx.x;
    __shared__ float al[49];
    if (t < 49) al[t] = alpha[b * L_ + q * 49 + t];
    __syncthreads();
    int kb = t >> 2, g = t & 3;
    int gm0 = b * L_ + q * 49;
    float acc[8] = {0.f, 0.f, 0.f, 0.f, 0.f, 0.f, 0.f, 0.f};
    for (int l0 = 0; l0 < 49; l0 += 7) {
        bf16x8 v[7];
        #pragma unroll
        for (int u = 0; u < 7; u++) {
            int gm = gm0 + l0 + u;
            int mt = gm >> 7, mr = gm & 127;
            v[u] = *reinterpret_cast<const bf16x8*>(
                encP + (size_t)mt * 262144 + kb * 4096 + mr * 32 +
                ((g ^ ((mr >> 1) & 3)) << 3));
        }
        #pragma unroll
        for (int u = 0; u < 7; u++) {
            float a = al[l0 + u];
            #pragma unroll
            for (int j = 0; j < 8; j++) {
                float x = __uint_as_float(((unsigned)(unsigned short)v[u][j]) << 16);
                acc[j] += a * x;
            }
        }
    }
    float* dst = aweP + ((size_t)(q * B_ + b)) * E_ + kb * 32 + g * 8;
    *reinterpret_cast<float4*>(dst)     = float4{acc[0], acc[1], acc[2], acc[3]};
    *reinterpret_cast<float4*>(dst + 4) = float4{acc[4], acc[5], acc[6], acc[7]};
}

// ---------------- k_awe_f32: fallback, reads fp32 enc ------------------------
__global__ __launch_bounds__(512) void k_awe_f32(const float* __restrict__ enc,
                                                 const float* __restrict__ alpha,
                                                 float* __restrict__ aweP) {
    int b = blockIdx.x >> 2, q = blockIdx.x & 3;
    int t = threadIdx.x;
    __shared__ float al[49];
    if (t < 49) al[t] = alpha[b * L_ + q * 49 + t];
    __syncthreads();
    const float* base = enc + ((size_t)b * L_ + (size_t)q * 49) * E_ + t * 4;
    float4 a0 = {0.f, 0.f, 0.f, 0.f}, a1 = a0, a2 = a0, a3 = a0;
    int l = 0;
    for (; l + 4 <= 48; l += 4) {
        float4 v0 = *reinterpret_cast<const float4*>(base + (size_t)l * E_);
        float4 v1 = *reinterpret_cast<const float4*>(base + (size_t)(l + 1) * E_);
        float4 v2 = *reinterpret_cast<const float4*>(base + (size_t)(l + 2) * E_);
        float4 v3 = *reinterpret_cast<const float4*>(base + (size_t)(l + 3) * E_);
        float c0 = al[l], c1 = al[l + 1], c2 = al[l + 2], c3 = al[l + 3];
        a0.x += c0 * v0.x; a0.y += c0 * v0.y; a0.z += c0 * v0.z; a0.w += c0 * v0.w;
        a1.x += c1 * v1.x; a1.y += c1 * v1.y; a1.z += c1 * v1.z; a1.w += c1 * v1.w;
        a2.x += c2 * v2.x; a2.y += c2 * v2.y; a2.z += c2 * v2.z; a2.w += c2 * v2.w;
        a3.x += c3 * v3.x; a3.y += c3 * v3.y; a3.z += c3 * v3.z; a3.w += c3 * v3.w;
    }
    {
        float4 v0 = *reinterpret_cast<const float4*>(base + (size_t)48 * E_);
        float c0 = al[48];
        a0.x += c0 * v0.x; a0.y += c0 * v0.y; a0.z += c0 * v0.z; a0.w += c0 * v0.w;
    }
    float4 o;
    o.x = (a0.x + a1.x) + (a2.x + a3.x);
    o.y = (a0.y + a1.y) + (a2.y + a3.y);
    o.z = (a0.z + a1.z) + (a2.z + a3.z);
    o.w = (a0.w + a1.w) + (a2.w + a3.w);
    *reinterpret_cast<float4*>(aweP + ((size_t)(q * B_ + b)) * E_ + t * 4) = o;
}

// ---------------- k_awecomb: sum 4 partials ----------------------------------
__global__ __launch_bounds__(256) void k_awecomb(const float* __restrict__ aweP,
                                                 float* __restrict__ awe) {
    int i = blockIdx.x * 256 + threadIdx.x;
    const float4* p = reinterpret_cast<const float4*>(aweP);
    const size_t S = (size_t)B_ * E_ / 4;
    float4 r0 = p[i], r1 = p[S + i], r2 = p[2 * S + i], r3 = p[3 * S + i];
    float4 o;
    o.x = (r0.x + r1.x) + (r2.x + r3.x);
    o.y = (r0.y + r1.y) + (r2.y + r3.y);
    o.z = (r0.z + r1.z) + (r2.z + r3.z);
    o.w = (r0.w + r1.w) + (r2.w + r3.w);
    reinterpret_cast<float4*>(awe)[i] = o;
}

extern "C" void kernel_launch(void* const* d_in, const int* in_sizes, int n_in,
                              void* d_out, int out_size, void* d_ws, size_t ws_size,
                              hipStream_t stream) {
    const float* enc  = (const float*)d_in[0];
    const float* dec  = (const float*)d_in[1];
    const int*   mask = (const int*)d_in[2];
    const float* We   = (const float*)d_in[3];
    const float* be   = (const float*)d_in[4];
    const float* Wd   = (const float*)d_in[5];
    const float* bd   = (const float*)d_in[6];
    const float* wf   = (const float*)d_in[7];
    const float* bf   = (const float*)d_in[8];

    float* awe   = (float*)d_out;                  // [256][2048]
    float* alpha = awe + (size_t)B_ * E_;          // [256][196]

    char* ws = (char*)d_ws;
    unsigned short* WeP = (unsigned short*)ws;                        // @0,      2 MB
    float* bias2   = (float*)(ws + 2097152);                          // @2 MB,   512 KB
    float* scoresP = (float*)(ws + 2621440);                          // @2.5 MB, 803 KB
    float* aweP    = (float*)(ws + 3670016);                          // @3.5 MB, 8 MB
    unsigned short* encP = (unsigned short*)(ws + 12582912);          // @12 MB,  206 MB
    const size_t NEED_BIG = 12582912u + 205520896u;
    const bool bigws = (ws_size >= NEED_BIG);

    hipLaunchKernelGGL(k_wepack, dim3((E_ * A_) / 256), dim3(256), 0, stream, We, WeP);
    hipLaunchKernelGGL(k_bias2, dim3(B_ / 4), dim3(256), 0, stream, dec, Wd, be, bd, bias2);
    if (bigws) {
        hipLaunchKernelGGL(k_encpack, dim3(392 * 8), dim3(256), 0, stream, enc, encP);
        hipLaunchKernelGGL(k_gemm_bf16, dim3(1568), dim3(256), 0, stream,
                           encP, WeP, bias2, wf, scoresP);
    } else {
        hipLaunchKernelGGL(k_gemm_f32, dim3(1568), dim3(256), 0, stream,
                           enc, WeP, bias2, wf, scoresP);
    }
    hipLaunchKernelGGL(k_softmax, dim3(B_), dim3(256), 0, stream, scoresP, mask, bf, alpha);
    if (bigws) {
        hipLaunchKernelGGL(k_awe_bf16, dim3(B_ * 4), dim3(256), 0, stream, encP, alpha, aweP);
    } else {
        hipLaunchKernelGGL(k_awe_f32, dim3(B_ * 4), dim3(512), 0, stream, enc, alpha, aweP);
    }
    hipLaunchKernelGGL(k_awecomb, dim3((B_ * E_ / 4) / 256), dim3(256), 0, stream, aweP, awe);
}

// Round 9
// 437.581 us; speedup vs baseline: 1.3430x; 1.3430x over previous
//
#include <hip/hip_runtime.h>
#include <hip/hip_bf16.h>

// Attention_50946902065218: Bahdanau-style attention
// B=256, L=196, E=2048, D=1024, A=512
// v9 pipeline:
//  k_wepack: We fp32 -> bf16, [kb][n][slot^swz(n)][e] pre-swizzled (2 MB)
//  k_bias2 : bias2[b][a] = be + bd + dec@Wd
//  k_gemm_score (v9): 128x128 tile, 4 waves 2x2, BK=32.
//     TRIPLE-buffered LDS, stage depth 2, counted vmcnt(6) raw barriers:
//     B(t+2) gload_lds + A(t+3) reg-loads stay in flight across barriers.
//     A reg-staged fp32->bf16 (3-deep static rotation avA/avB/avC).
//     XCD-chunked block swizzle (4 nt-siblings share A-panel in L2).
//     Fused tanh + wf-dot epilogue -> scoresP[4][M]
//  k_softmax: sum 4 partials + mask + softmax over L -> alpha
//  k_awe   : alpha-weighted enc reduction (r5's measured version)

#define B_ 256
#define L_ 196
#define E_ 2048
#define D_ 1024
#define A_ 512
#define M_TOT (B_ * L_)   // 50176 = 392 * 128

typedef __attribute__((ext_vector_type(8))) short bf16x8;
typedef __attribute__((ext_vector_type(4))) float f32x4;

static __device__ __forceinline__ unsigned short f2bf(float f) {
    union { float f; unsigned u; } u{f};
    unsigned r = u.u + 0x7fffu + ((u.u >> 16) & 1u);   // RNE
    return (unsigned short)(r >> 16);
}
static __device__ __forceinline__ unsigned int pk2(float x, float y) {
    __hip_bfloat162 h = __float22bfloat162_rn(float2{x, y});   // v_cvt_pk_bf16_f32
    return *reinterpret_cast<unsigned int*>(&h);
}
static __device__ __forceinline__ void gload_lds16(const void* g, void* l) {
    __builtin_amdgcn_global_load_lds(
        (const __attribute__((address_space(1))) unsigned int*)g,
        (__attribute__((address_space(3))) unsigned int*)l, 16, 0, 0);
}

// ---------------- k_wepack: We (E x A fp32) -> WeP bf16 ----------------------
// (k,n): kb=k>>5, slot=(k>>3)&3, e=k&7; stored slot' = slot ^ ((n>>1)&3).
// Index = kb*16384 + n*32 + slot'*8 + e. Fragment read (16 lanes n=base+lr,
// fixed kg) spreads over 8 16B-slots -> 2 lanes/bank (free).
__global__ __launch_bounds__(256) void k_wepack(const float* __restrict__ We,
                                                unsigned short* __restrict__ WeP) {
    int i = blockIdx.x * 256 + threadIdx.x;
    int k = i >> 9, n = i & 511;
    int kb = k >> 5, slot = (k >> 3) & 3, e = k & 7;
    int slotE = slot ^ ((n >> 1) & 3);
    WeP[(kb << 14) + (n << 5) + (slotE << 3) + e] = f2bf(We[i]);
}

// ---------------- k_bias2: bias2 = be + bd + dec @ Wd ------------------------
__global__ __launch_bounds__(256) void k_bias2(const float* __restrict__ dec,
                                               const float* __restrict__ Wd,
                                               const float* __restrict__ be,
                                               const float* __restrict__ bd,
                                               float* __restrict__ bias2) {
    int b = blockIdx.x, t = threadIdx.x;
    __shared__ float ds[D_];
    for (int i = t; i < D_; i += 256) ds[i] = dec[b * D_ + i];
    __syncthreads();
    for (int a0 = 0; a0 < A_; a0 += 256) {
        int a = a0 + t;
        float acc = 0.f;
        #pragma unroll 8
        for (int d = 0; d < D_; d++) acc += ds[d] * Wd[d * A_ + a];
        bias2[b * A_ + a] = acc + be[a] + bd[a];
    }
}

// ---------------- k_gemm_score v9 --------------------------------------------
// 1568 blocks (392 mt x 4 nt, XCD-chunked), 256 thr, 4 waves 2x2, wave 64x64.
__global__ __launch_bounds__(256, 3) void k_gemm_score(
        const float* __restrict__ enc,
        const unsigned short* __restrict__ WeP,
        const float* __restrict__ bias2,
        const float* __restrict__ wf,
        float* __restrict__ scoresP) {
    __shared__ __align__(16) unsigned short aL[3][4096];   // 8 KB each
    __shared__ __align__(16) unsigned short bL[3][4096];   // 8 KB each
    __shared__ float score_lds[4][64];

    const int tid = threadIdx.x;
    const int raw = blockIdx.x;                 // 1568 = 8 * 196
    const int wg = (raw & 7) * 196 + (raw >> 3);
    const int mt = wg >> 2, nt = wg & 3;
    const int m0 = mt * 128;

    const int lane = tid & 63, wid = tid >> 6;
    const int wm = wid >> 1, wn = wid & 1;
    const int kg = lane >> 4, lr = lane & 15;

    // A staging: 2 threads per row; thread covers 16 fp32 (k-half kh)
    const int ar = tid >> 1, kh = tid & 1;
    const float* aSrc = enc + (size_t)(m0 + ar) * E_ + kh * 16;
    const int sw = (ar >> 1) & 3;
    const int aOff0 = ar * 32 + ((((kh << 1) | 0) ^ sw) << 3);
    const int aOff1 = ar * 32 + ((((kh << 1) | 1) ^ sw) << 3);

    // B staging: 2 x gload_lds16 per thread, linear 8KB nt-slice (pre-swizzled)
    const unsigned short* bSrc = WeP + nt * 4096 + tid * 8;

    auto stageB = [&](int kb, int buf) {
        const unsigned short* s = bSrc + (kb << 14);
        gload_lds16(s,        &bL[buf][tid * 8]);
        gload_lds16(s + 2048, &bL[buf][2048 + tid * 8]);
    };
    auto loadA = [&](float4 (&v)[4], int kb) {
        const float* p = aSrc + (kb << 5);
        v[0] = *reinterpret_cast<const float4*>(p);
        v[1] = *reinterpret_cast<const float4*>(p + 4);
        v[2] = *reinterpret_cast<const float4*>(p + 8);
        v[3] = *reinterpret_cast<const float4*>(p + 12);
    };
    auto writeA = [&](const float4 (&v)[4], int buf) {
        uint4 q0, q1;
        q0.x = pk2(v[0].x, v[0].y); q0.y = pk2(v[0].z, v[0].w);
        q0.z = pk2(v[1].x, v[1].y); q0.w = pk2(v[1].z, v[1].w);
        q1.x = pk2(v[2].x, v[2].y); q1.y = pk2(v[2].z, v[2].w);
        q1.z = pk2(v[3].x, v[3].y); q1.w = pk2(v[3].z, v[3].w);
        *reinterpret_cast<uint4*>(&aL[buf][aOff0]) = q0;
        *reinterpret_cast<uint4*>(&aL[buf][aOff1]) = q1;
    };

    f32x4 acc[4][4];
    #pragma unroll
    for (int i = 0; i < 4; i++)
        #pragma unroll
        for (int j = 0; j < 4; j++) acc[i][j] = (f32x4){0.f, 0.f, 0.f, 0.f};

    auto computeTile = [&](int buf) {
        bf16x8 bfr[4];
        #pragma unroll
        for (int j = 0; j < 4; j++) {
            int n = wn * 64 + j * 16 + lr;
            bfr[j] = *reinterpret_cast<const bf16x8*>(
                &bL[buf][n * 32 + ((kg ^ ((n >> 1) & 3)) << 3)]);
        }
        #pragma unroll
        for (int i = 0; i < 4; i++) {
            int row = wm * 64 + i * 16 + lr;
            bf16x8 af = *reinterpret_cast<const bf16x8*>(
                &aL[buf][row * 32 + ((kg ^ ((row >> 1) & 3)) << 3)]);
            #pragma unroll
            for (int j = 0; j < 4; j++)
                acc[i][j] = __builtin_amdgcn_mfma_f32_16x16x32_bf16(
                    af, bfr[j], acc[i][j], 0, 0, 0);
        }
    };

    float4 avA[4], avB[4], avC[4];
    int t = 0;

    // one pipeline step (buf constants folded per call site):
    //   stage B(t+2), load A(t+3), compute(t), write A(t+1), vmcnt(6), barrier
    auto step = [&](float4 (&wr)[4], float4 (&ld)[4],
                    int sbuf, int cbuf, int wbuf) {
        stageB(t + 2, sbuf);
        __builtin_amdgcn_sched_barrier(0);
        loadA(ld, t + 3);
        __builtin_amdgcn_sched_barrier(0);
        computeTile(cbuf);
        writeA(wr, wbuf);
        asm volatile("s_waitcnt vmcnt(6) lgkmcnt(0)" ::: "memory");
        __builtin_amdgcn_s_barrier();
        __builtin_amdgcn_sched_barrier(0);
        t++;
    };

    // --- prologue: B(0),B(1) staged; A(0),A(1),A(2) in regs; A(0) written ---
    stageB(0, 0);
    stageB(1, 1);
    __builtin_amdgcn_sched_barrier(0);
    loadA(avA, 0);
    loadA(avB, 1);
    loadA(avC, 2);
    __builtin_amdgcn_sched_barrier(0);
    writeA(avA, 0);                 // auto-waits A(0); older B(0),B(1) drain too
    asm volatile("s_waitcnt vmcnt(8) lgkmcnt(0)" ::: "memory");
    __builtin_amdgcn_s_barrier();
    __builtin_amdgcn_sched_barrier(0);

    // --- steady state: t = 0..59 (20 x unroll-3, static reg rotation) ---
    for (int u = 0; u < 20; u++) {
        step(avB, avA, 2, 0, 1);    // t%3==0
        step(avC, avB, 0, 1, 2);    // t%3==1
        step(avA, avC, 1, 2, 0);    // t%3==2
    }
    // --- tail ---
    step(avB, avA, 2, 0, 1);        // t=60: stage B(62), load A(63)
    // t=61: stage B(63) only
    stageB(63, 0);
    __builtin_amdgcn_sched_barrier(0);
    computeTile(1);
    writeA(avC, 2);
    asm volatile("s_waitcnt vmcnt(6) lgkmcnt(0)" ::: "memory");   // drains B(62)
    __builtin_amdgcn_s_barrier();
    __builtin_amdgcn_sched_barrier(0);
    // t=62: no issues
    computeTile(2);
    writeA(avA, 0);                 // auto-waits A(63)
    asm volatile("s_waitcnt vmcnt(0) lgkmcnt(0)" ::: "memory");   // drains B(63)
    __builtin_amdgcn_s_barrier();
    __builtin_amdgcn_sched_barrier(0);
    // t=63
    computeTile(0);

    // --- epilogue: tanh + wf dot over this block's 128 cols -> partials ---
    #pragma unroll
    for (int i = 0; i < 4; i++) {
        #pragma unroll
        for (int r = 0; r < 4; r++) {
            int Rw = i * 16 + kg * 4 + r;   // C/D: col=lane&15, row=(lane>>4)*4+reg
            int gm = m0 + wm * 64 + Rw;
            int bg = gm / L_;
            float sum = 0.f;
            #pragma unroll
            for (int j = 0; j < 4; j++) {
                int C = nt * 128 + wn * 64 + j * 16 + lr;
                float x = acc[i][j][r] + bias2[bg * A_ + C];
                float ex = __expf(2.f * x);     // tanh = 1 - 2/(e^2x + 1)
                sum += wf[C] * (1.f - 2.f * __builtin_amdgcn_rcpf(ex + 1.f));
            }
            #pragma unroll
            for (int mk = 1; mk < 16; mk <<= 1) sum += __shfl_xor(sum, mk);
            if (lr == 0) score_lds[wid][Rw] = sum;
        }
    }
    __syncthreads();
    if (tid < 128) {
        int wmp = tid >> 6, rl = tid & 63;
        float s = score_lds[wmp * 2][rl] + score_lds[wmp * 2 + 1][rl];
        scoresP[nt * M_TOT + m0 + wmp * 64 + rl] = s;
    }
}

// ---------------- k_softmax: sum 4 partials + mask + softmax -----------------
__global__ __launch_bounds__(256) void k_softmax(const float* __restrict__ scoresP,
                                                 const int* __restrict__ mask,
                                                 const float* __restrict__ bfp,
                                                 float* __restrict__ alpha) {
    int b = blockIdx.x, t = threadIdx.x;
    float bfv = bfp[0];
    float v = -INFINITY;
    if (t < L_) {
        int idx = b * L_ + t;
        float sc = scoresP[idx] + scoresP[M_TOT + idx] +
                   scoresP[2 * M_TOT + idx] + scoresP[3 * M_TOT + idx];
        v = (mask[idx] == 0) ? -1e9f : (sc + bfv);
    }
    __shared__ float redm[4], reds[4];
    float m = v;
    #pragma unroll
    for (int s = 1; s < 64; s <<= 1) m = fmaxf(m, __shfl_xor(m, s));
    int w = t >> 6;
    if ((t & 63) == 0) redm[w] = m;
    __syncthreads();
    m = fmaxf(fmaxf(redm[0], redm[1]), fmaxf(redm[2], redm[3]));
    float e = (t < L_) ? expf(v - m) : 0.f;
    float s = e;
    #pragma unroll
    for (int k = 1; k < 64; k <<= 1) s += __shfl_xor(s, k);
    if ((t & 63) == 0) reds[w] = s;
    __syncthreads();
    s = reds[0] + reds[1] + reds[2] + reds[3];
    if (t < L_) alpha[b * L_ + t] = e / s;
}

// ---------------- k_awe: awe = sum_l alpha * enc  (r5's measured version) ----
// grid (8 e-chunks of 256, 256 batches), 256 threads = 4 groups x 64 lanes.
__global__ __launch_bounds__(256) void k_awe(const float* __restrict__ enc,
                                             const float* __restrict__ alpha,
                                             float* __restrict__ awe) {
    int b = blockIdx.y, ec = blockIdx.x, t = threadIdx.x;
    int g = t >> 6, lt = t & 63;
    __shared__ float al[L_];
    __shared__ float4 red[256];
    if (t < L_) al[t] = alpha[b * L_ + t];
    __syncthreads();
    int e0 = (ec << 8) + (lt << 2);
    const float* base = enc + (size_t)b * L_ * E_ + e0;
    float4 acc = {0.f, 0.f, 0.f, 0.f};
    int l0 = g * 49;
    #pragma unroll 7
    for (int l = l0; l < l0 + 49; l++) {
        float4 v = *reinterpret_cast<const float4*>(base + (size_t)l * E_);
        float a = al[l];
        acc.x += a * v.x; acc.y += a * v.y; acc.z += a * v.z; acc.w += a * v.w;
    }
    red[t] = acc;
    __syncthreads();
    if (t < 64) {
        float4 r0 = red[t], r1 = red[64 + t], r2 = red[128 + t], r3 = red[192 + t];
        float4 o;
        o.x = r0.x + r1.x + r2.x + r3.x;
        o.y = r0.y + r1.y + r2.y + r3.y;
        o.z = r0.z + r1.z + r2.z + r3.z;
        o.w = r0.w + r1.w + r2.w + r3.w;
        *reinterpret_cast<float4*>(awe + b * E_ + (ec << 8) + (t << 2)) = o;
    }
}

extern "C" void kernel_launch(void* const* d_in, const int* in_sizes, int n_in,
                              void* d_out, int out_size, void* d_ws, size_t ws_size,
                              hipStream_t stream) {
    const float* enc  = (const float*)d_in[0];
    const float* dec  = (const float*)d_in[1];
    const int*   mask = (const int*)d_in[2];
    const float* We   = (const float*)d_in[3];
    const float* be   = (const float*)d_in[4];
    const float* Wd   = (const float*)d_in[5];
    const float* bd   = (const float*)d_in[6];
    const float* wf   = (const float*)d_in[7];
    const float* bf   = (const float*)d_in[8];

    float* awe   = (float*)d_out;                  // [256][2048]
    float* alpha = awe + (size_t)B_ * E_;          // [256][196]

    char* ws = (char*)d_ws;
    unsigned short* WeP = (unsigned short*)ws;                        // 2 MB
    float* bias2   = (float*)(ws + 2097152);                          // 512 KB
    float* scoresP = (float*)(ws + 2621440);                          // 803 KB

    hipLaunchKernelGGL(k_wepack, dim3((E_ * A_) / 256), dim3(256), 0, stream, We, WeP);
    hipLaunchKernelGGL(k_bias2, dim3(B_), dim3(256), 0, stream, dec, Wd, be, bd, bias2);
    hipLaunchKernelGGL(k_gemm_score, dim3(1568), dim3(256), 0, stream,
                       enc, WeP, bias2, wf, scoresP);
    hipLaunchKernelGGL(k_softmax, dim3(B_), dim3(256), 0, stream, scoresP, mask, bf, alpha);
    hipLaunchKernelGGL(k_awe, dim3(8, B_), dim3(256), 0, stream, enc, alpha, awe);
}